// Round 19
// baseline (90.765 us; speedup 1.0000x reference)
//
#include <hip/hip_runtime.h>
#include <hip/hip_fp16.h>

// LGConv: out = D^{-1/2} A D^{-1/2} x
// x: f32 [N, 64]; edge_index: int32 on device (harness downcasts int64), [2, E]
//
// Pipeline:
//  K0 zero_kernel: zero bin_cnt.
//  K1 bin_kernel: per 4096-edge tile, LDS count(+rank)/scan/reorder by
//     dst-bin, sequential flush of packed 4B records ((dloc<<23)|src) +
//     directory. int4 edge loads, single LDS atomic per edge, wave-scan.
//  K3 csr_build: one block per bin; records in LDS once; single-pass
//     (node,bucket)-keyed counting sort (32 buckets) -> dis, row_ptr,
//     src-sorted rows; fused xs = dis*x fp16 staging (Path A).
//  K4 stage_xs (Path B only): xs overlaid on dead records region.
//  K5 gather_s: 4 nodes/wave, 16 lanes/node (8B col each); serial sorted
//     walk, unroll 8 (8 lines in flight), nontemporal csr, float4 store.

#define DFEAT 64
#define BIN_W 391          // nodes per bin; NB = ceil(N/BIN_W) must be <= 256
#define TILE 4096          // edges per K1 block (391 blocks -> better occupancy)
#define K1_THREADS 256
#define EPT (TILE / K1_THREADS)   // 16
#define DIRW 257
#define K3_THREADS 1024
#define MAX_NT 512         // NT must be <= this (and <= K3_THREADS)
#define CAP 8192           // LDS record capacity (mean 6250, +24 sigma)
#define NBUCK 32
#define KMAXP (BIN_W * NBUCK)            // 12512 keys (~50KB)
#define KPT ((KMAXP + K3_THREADS - 1) / K3_THREADS)  // 13 keys per thread

typedef unsigned long long u64;
typedef unsigned int u32;
typedef float f4v __attribute__((ext_vector_type(4)));

struct alignas(8) h4 { __half2 a, b; };   // 4 fp16 features

// ---------------- K0: zero bin_cnt ----------------
__global__ void zero_kernel(int* __restrict__ p, int n) {
    int i = blockIdx.x * blockDim.x + threadIdx.x;
    if (i < n) p[i] = 0;
}

// ---------------- K1: LDS-reordered binning, packed 4B records ----------------
__global__ __launch_bounds__(K1_THREADS)
void bin_kernel(const int* __restrict__ src, const int* __restrict__ dst,
                u32* __restrict__ records, int* __restrict__ dir,
                int* __restrict__ bin_cnt, int E, int N) {
    __shared__ int cnt[256];
    __shared__ int off[DIRW];
    __shared__ int wsum[5];
    __shared__ u32 buf[TILE];

    const int t    = blockIdx.x;
    const int base = t * TILE;
    const int tid  = threadIdx.x;
    const int lane = tid & 63, wave = tid >> 6;

    cnt[tid] = 0;
    __syncthreads();

    // phase A: vectorized load + count-with-rank (one LDS atomic per edge)
    u32 rec[EPT];
    int mybr[EPT];                  // (bin<<16)|rank, or -1
    #pragma unroll
    for (int j = 0; j < EPT / 4; ++j) {
        int e0 = base + 4 * (tid + j * K1_THREADS);
        int4 s4, d4;
        if (e0 + 3 < E) {
            s4 = *reinterpret_cast<const int4*>(src + e0);
            d4 = *reinterpret_cast<const int4*>(dst + e0);
        } else {
            s4.x = (e0 + 0 < E) ? src[e0 + 0] : -1;
            s4.y = (e0 + 1 < E) ? src[e0 + 1] : -1;
            s4.z = (e0 + 2 < E) ? src[e0 + 2] : -1;
            s4.w = (e0 + 3 < E) ? src[e0 + 3] : -1;
            d4.x = (e0 + 0 < E) ? dst[e0 + 0] : -1;
            d4.y = (e0 + 1 < E) ? dst[e0 + 1] : -1;
            d4.z = (e0 + 2 < E) ? dst[e0 + 2] : -1;
            d4.w = (e0 + 3 < E) ? dst[e0 + 3] : -1;
        }
        int ss[4] = { s4.x, s4.y, s4.z, s4.w };
        int dd[4] = { d4.x, d4.y, d4.z, d4.w };
        #pragma unroll
        for (int c = 0; c < 4; ++c) {
            int i = j * 4 + c;
            int b = -1;
            u32 r = 0;
            unsigned d = (unsigned)dd[c], s = (unsigned)ss[c];
            if (d < (unsigned)N && s < (unsigned)N) {
                b = (int)(d / BIN_W);
                r = ((d - (unsigned)b * BIN_W) << 23) | s;
            }
            rec[i] = r;
            mybr[i] = (b >= 0) ? ((b << 16) | atomicAdd(&cnt[b], 1)) : -1;
        }
    }
    __syncthreads();

    // phase B: wave-scan of cnt (exclusive)
    int v = cnt[tid];
    int sv = v;
    #pragma unroll
    for (int d = 1; d < 64; d <<= 1) {
        int tt = __shfl_up(sv, d);
        if (lane >= d) sv += tt;
    }
    if (lane == 63) wsum[wave] = sv;
    __syncthreads();
    if (tid == 0) {
        int a = 0;
        #pragma unroll
        for (int j = 0; j < 4; ++j) { int tt = wsum[j]; wsum[j] = a; a += tt; }
        wsum[4] = a;
    }
    __syncthreads();
    int excl = sv - v + wsum[wave];
    off[tid] = excl;
    if (tid == 0) off[256] = wsum[4];

    dir[t * DIRW + tid] = excl;
    if (tid == 0) dir[t * DIRW + 256] = wsum[4];
    if (v > 0) atomicAdd(&bin_cnt[tid], v);
    __syncthreads();

    // phase C: place records into LDS at binned positions (rank precomputed)
    #pragma unroll
    for (int i = 0; i < EPT; ++i) {
        int br = mybr[i];
        if (br >= 0)
            buf[off[br >> 16] + (br & 0xFFFF)] = rec[i];
    }
    __syncthreads();

    // phase D: sequential coalesced flush
    int total = off[256];
    for (int i = tid; i < total; i += K1_THREADS)
        records[(size_t)base + i] = buf[i];
}

// ---------------- block-wide exclusive scan helper (1024 thr, 2 barriers) ----------------
__device__ __forceinline__ int block_scan_excl(int v, int* wsum, int tid) {
    const int lane = tid & 63, wave = tid >> 6;
    int sv = v;
    #pragma unroll
    for (int d = 1; d < 64; d <<= 1) {
        int tt = __shfl_up(sv, d);
        if (lane >= d) sv += tt;
    }
    if (lane == 63) wsum[wave] = sv;
    __syncthreads();
    if (tid == 0) {
        int a = 0;
        #pragma unroll
        for (int j = 0; j < 16; ++j) { int tt = wsum[j]; wsum[j] = a; a += tt; }
        wsum[16] = a;                       // total
    }
    __syncthreads();
    return sv - v + wsum[wave];
}

// ---------------- K3: per-bin CSR build (+ optional fused xs staging) ----------------
__global__ __launch_bounds__(K3_THREADS)
void csr_build_kernel(const u32* __restrict__ records,
                      const int* __restrict__ dir,
                      const int* __restrict__ bin_cnt,
                      float* __restrict__ dis,
                      int* __restrict__ row_ptr,
                      int* __restrict__ csr_src,
                      const float* __restrict__ x,   // for fused staging
                      h4* __restrict__ xs,           // nullptr -> no staging
                      int N, int NT, int NB, int bshift) {
    __shared__ u32 ldsrec[CAP];       // 32KB
    __shared__ int cnt2[KMAXP];       // ~50KB: histogram, then cursors
    __shared__ float disl[BIN_W];     // dis values for fused staging
    __shared__ int wsum[17];
    __shared__ int sbeg[MAX_NT];
    __shared__ int send[MAX_NT];
    __shared__ int lofs[MAX_NT];
    __shared__ int sh_total, sh_gb0;

    const int b  = blockIdx.x;
    const int lo = b * BIN_W;
    const int nodes = min(BIN_W, N - lo);
    const int tid = threadIdx.x;
    const int wave = tid >> 6, lane = tid & 63;

    // --- bin_base scan ---
    int bv = (tid < NB) ? bin_cnt[tid] : 0;
    int excl = block_scan_excl(bv, wsum, tid);
    if (tid == b) sh_gb0 = excl;
    if (b == 0 && tid == 0) row_ptr[N] = wsum[16];
    __syncthreads();

    // --- run bounds + LDS-offset scan (NT <= K3_THREADS) ---
    int len = 0;
    if (tid < NT) {
        sbeg[tid] = dir[tid * DIRW + b];
        send[tid] = dir[tid * DIRW + b + 1];
        len = send[tid] - sbeg[tid];
    }
    int excl2 = block_scan_excl(len, wsum, tid);
    if (tid < NT) lofs[tid] = excl2;
    if (tid == 0) sh_total = wsum[16];
    __syncthreads();

    const int total = sh_total;
    const bool fits = (total <= CAP);

    // --- copy records into LDS: 4 runs per wave (16 lanes each) ---
    if (fits) {
        for (int rb = wave * 4; rb < NT; rb += 64) {
            int r = rb + (lane >> 4);
            if (r < NT) {
                int g0  = r * TILE + sbeg[r];
                int l0  = lofs[r];
                int ln  = send[r] - sbeg[r];
                for (int k = (lane & 15); k < ln; k += 16)
                    ldsrec[l0 + k] = records[g0 + k];
            }
        }
    }
    __syncthreads();

    // --- keyed histogram: key = dloc*NBUCK + (src>>bshift) ---
    for (int i = tid; i < KMAXP; i += K3_THREADS) cnt2[i] = 0;
    __syncthreads();
    if (fits) {
        for (int i = tid; i < total; i += K3_THREADS) {
            u32 r = ldsrec[i];
            int key = (int)(r >> 23) * NBUCK + (int)((r & 0x7FFFFF) >> bshift);
            atomicAdd(&cnt2[key], 1);
        }
    } else {
        for (int t = wave; t < NT; t += 16) {
            int s = sbeg[t], e = send[t], gb = t * TILE;
            for (int k = s + lane; k < e; k += 64) {
                u32 r = records[gb + k];
                int key = (int)(r >> 23) * NBUCK + (int)((r & 0x7FFFFF) >> bshift);
                atomicAdd(&cnt2[key], 1);
            }
        }
    }
    __syncthreads();

    // --- dis from per-node bucket sums ---
    if (tid < nodes) {
        int c = 0;
        #pragma unroll
        for (int j = 0; j < NBUCK; ++j) c += cnt2[tid * NBUCK + j];
        float w = (c > 0) ? rsqrtf((float)c) : 0.0f;
        dis[lo + tid] = w;
        disl[tid] = w;
    }

    // --- ownership scan over KMAXP keys (KPT per thread) ---
    int base7 = tid * KPT;
    int loc[KPT];
    int s = 0;
    #pragma unroll
    for (int j = 0; j < KPT; ++j) {
        int k = base7 + j;
        loc[j] = s;
        if (k < KMAXP) s += cnt2[k];
    }
    int excl3 = block_scan_excl(s, wsum, tid);
    __syncthreads();
    #pragma unroll
    for (int j = 0; j < KPT; ++j) {
        int k = base7 + j;
        if (k < KMAXP) cnt2[k] = sh_gb0 + excl3 + loc[j];
    }
    __syncthreads();

    // --- row_ptr = cursor of each node's bucket 0 (before scatter mutates) ---
    if (tid < nodes) row_ptr[lo + tid] = cnt2[tid * NBUCK];
    __syncthreads();

    // --- single scatter pass (bucket-sorted rows via key order) ---
    if (fits) {
        for (int i = tid; i < total; i += K3_THREADS) {
            u32 r = ldsrec[i];
            u32 sc = r & 0x7FFFFF;
            int key = (int)(r >> 23) * NBUCK + (int)(sc >> bshift);
            int pos = atomicAdd(&cnt2[key], 1);
            csr_src[pos] = (int)sc;
        }
    } else {
        for (int t = wave; t < NT; t += 16) {
            int s0 = sbeg[t], e0 = send[t], gb = t * TILE;
            for (int k = s0 + lane; k < e0; k += 64) {
                u32 r = records[gb + k];
                u32 sc = r & 0x7FFFFF;
                int key = (int)(r >> 23) * NBUCK + (int)(sc >> bshift);
                int pos = atomicAdd(&cnt2[key], 1);
                csr_src[pos] = (int)sc;
            }
        }
    }

    // --- fused xs staging for this bin's nodes (Path A) ---
    if (xs != nullptr) {
        const f4v* x4 = reinterpret_cast<const f4v*>(x);
        for (int i = tid; i < nodes * 16; i += K3_THREADS) {
            int nl = i >> 4;
            int c  = i & 15;
            float w = disl[nl];
            f4v f = __builtin_nontemporal_load(x4 + (size_t)(lo + nl) * 16 + c);
            h4 o;
            o.a = __floats2half2_rn(f.x * w, f.y * w);
            o.b = __floats2half2_rn(f.z * w, f.w * w);
            xs[(size_t)(lo + nl) * 16 + c] = o;
        }
    }
}

// ---------------- K4 (Path B): stage xs = dis[s] * x[s] -> fp16 ----------------
__global__ __launch_bounds__(256)
void stage_xs_kernel(const float* __restrict__ x, const float* __restrict__ dis,
                     __half2* __restrict__ xs, int total4 /* N*DFEAT/4 */) {
    int i = blockIdx.x * blockDim.x + threadIdx.x;
    if (i < total4) {
        float w = dis[i >> 4];   // 16 float4 per node
        float4 f = *reinterpret_cast<const float4*>(x + (size_t)i * 4);
        xs[i * 2]     = __floats2half2_rn(f.x * w, f.y * w);
        xs[i * 2 + 1] = __floats2half2_rn(f.z * w, f.w * w);
    }
}

// ---------------- K5: gather — 4 nodes/wave, serial src-sorted walk, unroll 8 ----------------
__global__ void gather_s_kernel(const h4* __restrict__ xs4,
                                const int* __restrict__ row_ptr,
                                const int* __restrict__ csr_src,
                                const float* __restrict__ dis,
                                float* __restrict__ out, int N) {
    long long gt = blockIdx.x * (long long)blockDim.x + threadIdx.x;
    int node = (int)((gt >> 6) * 4) + ((threadIdx.x & 63) >> 4);
    int c8 = threadIdx.x & 15;
    if (node >= N) return;
    int beg = row_ptr[node];
    int end = row_ptr[node + 1];
    float a0 = 0.0f, a1 = 0.0f, a2 = 0.0f, a3 = 0.0f;
    int k = beg;
    for (; k + 7 < end; k += 8) {          // 8 sorted lines in flight
        int s0 = __builtin_nontemporal_load(csr_src + k);
        int s1 = __builtin_nontemporal_load(csr_src + k + 1);
        int s2 = __builtin_nontemporal_load(csr_src + k + 2);
        int s3 = __builtin_nontemporal_load(csr_src + k + 3);
        int s4 = __builtin_nontemporal_load(csr_src + k + 4);
        int s5 = __builtin_nontemporal_load(csr_src + k + 5);
        int s6 = __builtin_nontemporal_load(csr_src + k + 6);
        int s7 = __builtin_nontemporal_load(csr_src + k + 7);
        h4 v0 = xs4[(size_t)s0 * 16 + c8];
        h4 v1 = xs4[(size_t)s1 * 16 + c8];
        h4 v2 = xs4[(size_t)s2 * 16 + c8];
        h4 v3 = xs4[(size_t)s3 * 16 + c8];
        h4 v4 = xs4[(size_t)s4 * 16 + c8];
        h4 v5 = xs4[(size_t)s5 * 16 + c8];
        h4 v6 = xs4[(size_t)s6 * 16 + c8];
        h4 v7 = xs4[(size_t)s7 * 16 + c8];
        float2 f0 = __half22float2(v0.a), g0 = __half22float2(v0.b);
        float2 f1 = __half22float2(v1.a), g1 = __half22float2(v1.b);
        float2 f2 = __half22float2(v2.a), g2 = __half22float2(v2.b);
        float2 f3 = __half22float2(v3.a), g3 = __half22float2(v3.b);
        float2 f4 = __half22float2(v4.a), g4 = __half22float2(v4.b);
        float2 f5 = __half22float2(v5.a), g5 = __half22float2(v5.b);
        float2 f6 = __half22float2(v6.a), g6 = __half22float2(v6.b);
        float2 f7 = __half22float2(v7.a), g7 = __half22float2(v7.b);
        a0 += ((f0.x + f1.x) + (f2.x + f3.x)) + ((f4.x + f5.x) + (f6.x + f7.x));
        a1 += ((f0.y + f1.y) + (f2.y + f3.y)) + ((f4.y + f5.y) + (f6.y + f7.y));
        a2 += ((g0.x + g1.x) + (g2.x + g3.x)) + ((g4.x + g5.x) + (g6.x + g7.x));
        a3 += ((g0.y + g1.y) + (g2.y + g3.y)) + ((g4.y + g5.y) + (g6.y + g7.y));
    }
    for (; k + 1 < end; k += 2) {
        int s0 = __builtin_nontemporal_load(csr_src + k);
        int s1 = __builtin_nontemporal_load(csr_src + k + 1);
        h4 v0 = xs4[(size_t)s0 * 16 + c8];
        h4 v1 = xs4[(size_t)s1 * 16 + c8];
        float2 f0 = __half22float2(v0.a), g0 = __half22float2(v0.b);
        float2 f1 = __half22float2(v1.a), g1 = __half22float2(v1.b);
        a0 += f0.x + f1.x; a1 += f0.y + f1.y;
        a2 += g0.x + g1.x; a3 += g0.y + g1.y;
    }
    if (k < end) {
        int s0 = __builtin_nontemporal_load(csr_src + k);
        h4 v0 = xs4[(size_t)s0 * 16 + c8];
        float2 f0 = __half22float2(v0.a), g0 = __half22float2(v0.b);
        a0 += f0.x; a1 += f0.y; a2 += g0.x; a3 += g0.y;
    }
    float dd = dis[node];
    f4v o = { a0 * dd, a1 * dd, a2 * dd, a3 * dd };
    __builtin_nontemporal_store(o, (f4v*)(out + (size_t)node * DFEAT + c8 * 4));
}

// ---------------- fallback (atomic scatter) if ws too small ----------------
__global__ void fb_deg_kernel(const int* __restrict__ dst,
                              float* __restrict__ deg, int E, int N) {
    int e = blockIdx.x * blockDim.x + threadIdx.x;
    if (e < E) {
        unsigned d = (unsigned)dst[e];
        if (d < (unsigned)N) unsafeAtomicAdd(&deg[d], 1.0f);
    }
}
__global__ void fb_dis_kernel(float* __restrict__ deg, int N) {
    int i = blockIdx.x * blockDim.x + threadIdx.x;
    if (i < N) {
        float d = deg[i];
        deg[i] = (d > 0.0f) ? rsqrtf(d) : 0.0f;
    }
}
__global__ void fb_scatter_kernel(const float* __restrict__ x,
                                  const int* __restrict__ src,
                                  const int* __restrict__ dst,
                                  const float* __restrict__ dis,
                                  float* __restrict__ out, int E, int N) {
    long long t = (long long)blockIdx.x * blockDim.x + threadIdx.x;
    int e = (int)(t >> 4);
    int c = (int)(t & 15);
    if (e >= E) return;
    unsigned s = (unsigned)src[e];
    unsigned d = (unsigned)dst[e];
    if (s >= (unsigned)N || d >= (unsigned)N) return;
    float norm = dis[s] * dis[d];
    const float4 v = *reinterpret_cast<const float4*>(x + (size_t)s * DFEAT + c * 4);
    float* o = out + (size_t)d * DFEAT + c * 4;
    unsafeAtomicAdd(o + 0, v.x * norm);
    unsafeAtomicAdd(o + 1, v.y * norm);
    unsafeAtomicAdd(o + 2, v.z * norm);
    unsafeAtomicAdd(o + 3, v.w * norm);
}

extern "C" void kernel_launch(void* const* d_in, const int* in_sizes, int n_in,
                              void* d_out, int out_size, void* d_ws, size_t ws_size,
                              hipStream_t stream) {
    const float* x  = (const float*)d_in[0];
    const int*   ei = (const int*)d_in[1];   // harness delivers integer inputs as int32

    const int N = in_sizes[0] / DFEAT;        // 100000
    const int E = in_sizes[1] / 2;            // 1600000
    const int* src = ei;                      // row 0
    const int* dst = ei + E;                  // row 1

    float* out = (float*)d_out;

    const int NB = (N + BIN_W - 1) / BIN_W;   // bins (256 for N=100000)
    const int NT = (E + TILE - 1) / TILE;     // tiles (391 for E=1.6M)

    // src bucket shift: <= NBUCK buckets over [0,N)
    int bshift = 12;
    while ((((N - 1) >> bshift) + 1) > NBUCK) bshift++;

    const size_t rec_bytes = (size_t)NT * TILE * 4;
    const size_t xs_bytes  = (size_t)N * DFEAT * 2;
    auto align16 = [](size_t v) { return (v + 15) & ~(size_t)15; };

    // Path A layout (xs separate, fused staging):
    size_t szA = align16(rec_bytes) + align16(xs_bytes);
    // Path B layout (xs overlays records):
    size_t szB = align16(rec_bytes > xs_bytes ? rec_bytes : xs_bytes);
    size_t tail = align16((size_t)NT * DIRW * 4) + align16(256 * 4) +
                  align16((size_t)N * 4) + align16((size_t)(N + 1) * 4) +
                  align16((size_t)E * 4);
    szA += tail; szB += tail;

    const bool structural = (NB <= 256) && (NT <= MAX_NT) && (NT <= K3_THREADS) &&
                            (N <= (1 << 23)) && (BIN_W <= 512);
    const bool pathA = structural && (szA <= ws_size);
    const bool pathB = structural && !pathA && (szB <= ws_size) &&
                       (rec_bytes <= szB - tail) && (xs_bytes <= szB - tail);

    if (pathA || pathB) {
        char* base = (char*)d_ws;
        size_t off = 0;
        auto alloc = [&](size_t bytes) { void* p = base + off; off += align16(bytes); return p; };

        u32* records; h4* xsA = nullptr; __half2* xsB = nullptr;
        if (pathA) {
            records = (u32*)alloc(rec_bytes);
            xsA     = (h4*)alloc(xs_bytes);
        } else {
            records = (u32*)alloc(rec_bytes > xs_bytes ? rec_bytes : xs_bytes);
            xsB     = (__half2*)records;       // overlay; records dead after K3
        }
        int*   dir      = (int*)alloc((size_t)NT * DIRW * 4);
        int*   bin_cnt  = (int*)alloc(256 * 4);
        float* dis      = (float*)alloc((size_t)N * 4);
        int*   row_ptr  = (int*)alloc((size_t)(N + 1) * 4);
        int*   csr_src  = (int*)alloc((size_t)E * 4);

        zero_kernel<<<1, 256, 0, stream>>>(bin_cnt, 256);
        bin_kernel<<<NT, K1_THREADS, 0, stream>>>(src, dst, records, dir, bin_cnt, E, N);
        csr_build_kernel<<<NB, K3_THREADS, 0, stream>>>(records, dir, bin_cnt, dis,
                                                        row_ptr, csr_src, x, xsA,
                                                        N, NT, NB, bshift);
        const h4* xs_final;
        if (pathA) {
            xs_final = xsA;
        } else {
            int total4 = N * DFEAT / 4;
            stage_xs_kernel<<<(total4 + 255) / 256, 256, 0, stream>>>(x, dis, xsB, total4);
            xs_final = (const h4*)xsB;
        }

        int gblocks = (N + 15) / 16;   // 16 nodes per 256-thread block
        gather_s_kernel<<<gblocks, 256, 0, stream>>>(xs_final, row_ptr, csr_src, dis, out, N);
    } else {
        // fallback: atomic scatter (needs only N floats of ws)
        float* deg = (float*)d_ws;
        hipMemsetAsync(deg, 0, (size_t)N * 4, stream);
        hipMemsetAsync(out, 0, (size_t)out_size * 4, stream);
        int eb = (E + 255) / 256;
        fb_deg_kernel<<<eb, 256, 0, stream>>>(dst, deg, E, N);
        int nb = (N + 255) / 256;
        fb_dis_kernel<<<nb, 256, 0, stream>>>(deg, N);
        long long total = (long long)E * 16;
        int sb = (int)((total + 255) / 256);
        fb_scatter_kernel<<<sb, 256, 0, stream>>>(x, src, dst, deg, out, E, N);
    }
}

// Round 20
// 86.061 us; speedup vs baseline: 1.0547x; 1.0547x over previous
//
#include <hip/hip_runtime.h>
#include <hip/hip_fp16.h>

// LGConv: out = D^{-1/2} A D^{-1/2} x
// x: f32 [N, 64]; edge_index: int32 on device (harness downcasts int64), [2, E]
//
// Pipeline (round-18 optimum):
//  K0 zero_kernel: zero bin_cnt.
//  K1 bin_kernel: per 8192-edge tile, LDS count(+rank)/scan/reorder by
//     dst-bin, sequential flush of packed 4B records ((dloc<<23)|src) +
//     directory. int4 edge loads, single LDS atomic per edge, wave-scan.
//  K3 csr_build: one block per bin; records in LDS once; single-pass
//     (node,bucket)-keyed counting sort (16 buckets) -> dis, row_ptr,
//     src-sorted rows; fused xs = dis*x fp16 staging (Path A).
//  K4 stage_xs (Path B only): xs overlaid on dead records region.
//  K5 gather_s: 4 nodes/wave, 16 lanes/node (8B col each); serial sorted
//     walk, unroll 8 (8 lines in flight), nontemporal csr, float4 store.

#define DFEAT 64
#define BIN_W 391          // nodes per bin; NB = ceil(N/BIN_W) must be <= 256
#define TILE 8192          // edges per K1 block
#define K1_THREADS 256
#define EPT (TILE / K1_THREADS)   // 32
#define DIRW 257
#define K3_THREADS 1024
#define MAX_NT 512         // NT must be <= this (and <= K3_THREADS)
#define CAP 8192           // LDS record capacity (mean 6250, +24 sigma)
#define NBUCK 16
#define KMAXP (BIN_W * NBUCK)            // 6256 keys
#define KPT ((KMAXP + K3_THREADS - 1) / K3_THREADS)  // 7 keys per thread

typedef unsigned long long u64;
typedef unsigned int u32;
typedef float f4v __attribute__((ext_vector_type(4)));

struct alignas(8) h4 { __half2 a, b; };   // 4 fp16 features

// ---------------- K0: zero bin_cnt ----------------
__global__ void zero_kernel(int* __restrict__ p, int n) {
    int i = blockIdx.x * blockDim.x + threadIdx.x;
    if (i < n) p[i] = 0;
}

// ---------------- K1: LDS-reordered binning, packed 4B records ----------------
__global__ __launch_bounds__(K1_THREADS)
void bin_kernel(const int* __restrict__ src, const int* __restrict__ dst,
                u32* __restrict__ records, int* __restrict__ dir,
                int* __restrict__ bin_cnt, int E, int N) {
    __shared__ int cnt[256];
    __shared__ int off[DIRW];
    __shared__ int wsum[5];
    __shared__ u32 buf[TILE];

    const int t    = blockIdx.x;
    const int base = t * TILE;
    const int tid  = threadIdx.x;
    const int lane = tid & 63, wave = tid >> 6;

    cnt[tid] = 0;
    __syncthreads();

    // phase A: vectorized load + count-with-rank (one LDS atomic per edge)
    u32 rec[EPT];
    int mybr[EPT];                  // (bin<<16)|rank, or -1
    #pragma unroll
    for (int j = 0; j < EPT / 4; ++j) {
        int e0 = base + 4 * (tid + j * K1_THREADS);
        int4 s4, d4;
        if (e0 + 3 < E) {
            s4 = *reinterpret_cast<const int4*>(src + e0);
            d4 = *reinterpret_cast<const int4*>(dst + e0);
        } else {
            s4.x = (e0 + 0 < E) ? src[e0 + 0] : -1;
            s4.y = (e0 + 1 < E) ? src[e0 + 1] : -1;
            s4.z = (e0 + 2 < E) ? src[e0 + 2] : -1;
            s4.w = (e0 + 3 < E) ? src[e0 + 3] : -1;
            d4.x = (e0 + 0 < E) ? dst[e0 + 0] : -1;
            d4.y = (e0 + 1 < E) ? dst[e0 + 1] : -1;
            d4.z = (e0 + 2 < E) ? dst[e0 + 2] : -1;
            d4.w = (e0 + 3 < E) ? dst[e0 + 3] : -1;
        }
        int ss[4] = { s4.x, s4.y, s4.z, s4.w };
        int dd[4] = { d4.x, d4.y, d4.z, d4.w };
        #pragma unroll
        for (int c = 0; c < 4; ++c) {
            int i = j * 4 + c;
            int b = -1;
            u32 r = 0;
            unsigned d = (unsigned)dd[c], s = (unsigned)ss[c];
            if (d < (unsigned)N && s < (unsigned)N) {
                b = (int)(d / BIN_W);
                r = ((d - (unsigned)b * BIN_W) << 23) | s;
            }
            rec[i] = r;
            mybr[i] = (b >= 0) ? ((b << 16) | atomicAdd(&cnt[b], 1)) : -1;
        }
    }
    __syncthreads();

    // phase B: wave-scan of cnt (exclusive)
    int v = cnt[tid];
    int sv = v;
    #pragma unroll
    for (int d = 1; d < 64; d <<= 1) {
        int tt = __shfl_up(sv, d);
        if (lane >= d) sv += tt;
    }
    if (lane == 63) wsum[wave] = sv;
    __syncthreads();
    if (tid == 0) {
        int a = 0;
        #pragma unroll
        for (int j = 0; j < 4; ++j) { int tt = wsum[j]; wsum[j] = a; a += tt; }
        wsum[4] = a;
    }
    __syncthreads();
    int excl = sv - v + wsum[wave];
    off[tid] = excl;
    if (tid == 0) off[256] = wsum[4];

    dir[t * DIRW + tid] = excl;
    if (tid == 0) dir[t * DIRW + 256] = wsum[4];
    if (v > 0) atomicAdd(&bin_cnt[tid], v);
    __syncthreads();

    // phase C: place records into LDS at binned positions (rank precomputed)
    #pragma unroll
    for (int i = 0; i < EPT; ++i) {
        int br = mybr[i];
        if (br >= 0)
            buf[off[br >> 16] + (br & 0xFFFF)] = rec[i];
    }
    __syncthreads();

    // phase D: sequential coalesced flush
    int total = off[256];
    for (int i = tid; i < total; i += K1_THREADS)
        records[(size_t)base + i] = buf[i];
}

// ---------------- block-wide exclusive scan helper (1024 thr, 2 barriers) ----------------
__device__ __forceinline__ int block_scan_excl(int v, int* wsum, int tid) {
    const int lane = tid & 63, wave = tid >> 6;
    int sv = v;
    #pragma unroll
    for (int d = 1; d < 64; d <<= 1) {
        int tt = __shfl_up(sv, d);
        if (lane >= d) sv += tt;
    }
    if (lane == 63) wsum[wave] = sv;
    __syncthreads();
    if (tid == 0) {
        int a = 0;
        #pragma unroll
        for (int j = 0; j < 16; ++j) { int tt = wsum[j]; wsum[j] = a; a += tt; }
        wsum[16] = a;                       // total
    }
    __syncthreads();
    return sv - v + wsum[wave];
}

// ---------------- K3: per-bin CSR build (+ optional fused xs staging) ----------------
__global__ __launch_bounds__(K3_THREADS)
void csr_build_kernel(const u32* __restrict__ records,
                      const int* __restrict__ dir,
                      const int* __restrict__ bin_cnt,
                      float* __restrict__ dis,
                      int* __restrict__ row_ptr,
                      int* __restrict__ csr_src,
                      const float* __restrict__ x,   // for fused staging
                      h4* __restrict__ xs,           // nullptr -> no staging
                      int N, int NT, int NB, int bshift) {
    __shared__ u32 ldsrec[CAP];       // 32KB
    __shared__ int cnt2[KMAXP];       // 25KB: histogram, then cursors
    __shared__ float disl[BIN_W];     // dis values for fused staging
    __shared__ int wsum[17];
    __shared__ int sbeg[MAX_NT];
    __shared__ int send[MAX_NT];
    __shared__ int lofs[MAX_NT];
    __shared__ int sh_total, sh_gb0;

    const int b  = blockIdx.x;
    const int lo = b * BIN_W;
    const int nodes = min(BIN_W, N - lo);
    const int tid = threadIdx.x;
    const int wave = tid >> 6, lane = tid & 63;

    // --- bin_base scan ---
    int bv = (tid < NB) ? bin_cnt[tid] : 0;
    int excl = block_scan_excl(bv, wsum, tid);
    if (tid == b) sh_gb0 = excl;
    if (b == 0 && tid == 0) row_ptr[N] = wsum[16];
    __syncthreads();

    // --- run bounds + LDS-offset scan (NT <= K3_THREADS) ---
    int len = 0;
    if (tid < NT) {
        sbeg[tid] = dir[tid * DIRW + b];
        send[tid] = dir[tid * DIRW + b + 1];
        len = send[tid] - sbeg[tid];
    }
    int excl2 = block_scan_excl(len, wsum, tid);
    if (tid < NT) lofs[tid] = excl2;
    if (tid == 0) sh_total = wsum[16];
    __syncthreads();

    const int total = sh_total;
    const bool fits = (total <= CAP);

    // --- copy records into LDS: 2 runs per wave (32 lanes each) ---
    if (fits) {
        for (int rb = wave * 2; rb < NT; rb += 32) {
            int r = rb + (lane >> 5);
            if (r < NT) {
                int g0  = r * TILE + sbeg[r];
                int l0  = lofs[r];
                int ln  = send[r] - sbeg[r];
                for (int k = (lane & 31); k < ln; k += 32)
                    ldsrec[l0 + k] = records[g0 + k];
            }
        }
    }
    __syncthreads();

    // --- keyed histogram: key = dloc*16 + (src>>bshift) ---
    for (int i = tid; i < KMAXP; i += K3_THREADS) cnt2[i] = 0;
    __syncthreads();
    if (fits) {
        for (int i = tid; i < total; i += K3_THREADS) {
            u32 r = ldsrec[i];
            int key = (int)(r >> 23) * NBUCK + (int)((r & 0x7FFFFF) >> bshift);
            atomicAdd(&cnt2[key], 1);
        }
    } else {
        for (int t = wave; t < NT; t += 16) {
            int s = sbeg[t], e = send[t], gb = t * TILE;
            for (int k = s + lane; k < e; k += 64) {
                u32 r = records[gb + k];
                int key = (int)(r >> 23) * NBUCK + (int)((r & 0x7FFFFF) >> bshift);
                atomicAdd(&cnt2[key], 1);
            }
        }
    }
    __syncthreads();

    // --- dis from per-node bucket sums ---
    if (tid < nodes) {
        int c = 0;
        #pragma unroll
        for (int j = 0; j < NBUCK; ++j) c += cnt2[tid * NBUCK + j];
        float w = (c > 0) ? rsqrtf((float)c) : 0.0f;
        dis[lo + tid] = w;
        disl[tid] = w;
    }

    // --- ownership scan over KMAXP keys (KPT per thread) ---
    int base7 = tid * KPT;
    int loc[KPT];
    int s = 0;
    #pragma unroll
    for (int j = 0; j < KPT; ++j) {
        int k = base7 + j;
        loc[j] = s;
        if (k < KMAXP) s += cnt2[k];
    }
    int excl3 = block_scan_excl(s, wsum, tid);
    __syncthreads();
    #pragma unroll
    for (int j = 0; j < KPT; ++j) {
        int k = base7 + j;
        if (k < KMAXP) cnt2[k] = sh_gb0 + excl3 + loc[j];
    }
    __syncthreads();

    // --- row_ptr = cursor of each node's bucket 0 (before scatter mutates) ---
    if (tid < nodes) row_ptr[lo + tid] = cnt2[tid * NBUCK];
    __syncthreads();

    // --- single scatter pass (bucket-sorted rows via key order) ---
    if (fits) {
        for (int i = tid; i < total; i += K3_THREADS) {
            u32 r = ldsrec[i];
            u32 sc = r & 0x7FFFFF;
            int key = (int)(r >> 23) * NBUCK + (int)(sc >> bshift);
            int pos = atomicAdd(&cnt2[key], 1);
            csr_src[pos] = (int)sc;
        }
    } else {
        for (int t = wave; t < NT; t += 16) {
            int s0 = sbeg[t], e0 = send[t], gb = t * TILE;
            for (int k = s0 + lane; k < e0; k += 64) {
                u32 r = records[gb + k];
                u32 sc = r & 0x7FFFFF;
                int key = (int)(r >> 23) * NBUCK + (int)(sc >> bshift);
                int pos = atomicAdd(&cnt2[key], 1);
                csr_src[pos] = (int)sc;
            }
        }
    }

    // --- fused xs staging for this bin's nodes (Path A) ---
    if (xs != nullptr) {
        const f4v* x4 = reinterpret_cast<const f4v*>(x);
        for (int i = tid; i < nodes * 16; i += K3_THREADS) {
            int nl = i >> 4;
            int c  = i & 15;
            float w = disl[nl];
            f4v f = __builtin_nontemporal_load(x4 + (size_t)(lo + nl) * 16 + c);
            h4 o;
            o.a = __floats2half2_rn(f.x * w, f.y * w);
            o.b = __floats2half2_rn(f.z * w, f.w * w);
            xs[(size_t)(lo + nl) * 16 + c] = o;
        }
    }
}

// ---------------- K4 (Path B): stage xs = dis[s] * x[s] -> fp16 ----------------
__global__ __launch_bounds__(256)
void stage_xs_kernel(const float* __restrict__ x, const float* __restrict__ dis,
                     __half2* __restrict__ xs, int total4 /* N*DFEAT/4 */) {
    int i = blockIdx.x * blockDim.x + threadIdx.x;
    if (i < total4) {
        float w = dis[i >> 4];   // 16 float4 per node
        float4 f = *reinterpret_cast<const float4*>(x + (size_t)i * 4);
        xs[i * 2]     = __floats2half2_rn(f.x * w, f.y * w);
        xs[i * 2 + 1] = __floats2half2_rn(f.z * w, f.w * w);
    }
}

// ---------------- K5: gather — 4 nodes/wave, serial src-sorted walk, unroll 8 ----------------
__global__ void gather_s_kernel(const h4* __restrict__ xs4,
                                const int* __restrict__ row_ptr,
                                const int* __restrict__ csr_src,
                                const float* __restrict__ dis,
                                float* __restrict__ out, int N) {
    long long gt = blockIdx.x * (long long)blockDim.x + threadIdx.x;
    int node = (int)((gt >> 6) * 4) + ((threadIdx.x & 63) >> 4);
    int c8 = threadIdx.x & 15;
    if (node >= N) return;
    int beg = row_ptr[node];
    int end = row_ptr[node + 1];
    float a0 = 0.0f, a1 = 0.0f, a2 = 0.0f, a3 = 0.0f;
    int k = beg;
    for (; k + 7 < end; k += 8) {          // 8 sorted lines in flight
        int s0 = __builtin_nontemporal_load(csr_src + k);
        int s1 = __builtin_nontemporal_load(csr_src + k + 1);
        int s2 = __builtin_nontemporal_load(csr_src + k + 2);
        int s3 = __builtin_nontemporal_load(csr_src + k + 3);
        int s4 = __builtin_nontemporal_load(csr_src + k + 4);
        int s5 = __builtin_nontemporal_load(csr_src + k + 5);
        int s6 = __builtin_nontemporal_load(csr_src + k + 6);
        int s7 = __builtin_nontemporal_load(csr_src + k + 7);
        h4 v0 = xs4[(size_t)s0 * 16 + c8];
        h4 v1 = xs4[(size_t)s1 * 16 + c8];
        h4 v2 = xs4[(size_t)s2 * 16 + c8];
        h4 v3 = xs4[(size_t)s3 * 16 + c8];
        h4 v4 = xs4[(size_t)s4 * 16 + c8];
        h4 v5 = xs4[(size_t)s5 * 16 + c8];
        h4 v6 = xs4[(size_t)s6 * 16 + c8];
        h4 v7 = xs4[(size_t)s7 * 16 + c8];
        float2 f0 = __half22float2(v0.a), g0 = __half22float2(v0.b);
        float2 f1 = __half22float2(v1.a), g1 = __half22float2(v1.b);
        float2 f2 = __half22float2(v2.a), g2 = __half22float2(v2.b);
        float2 f3 = __half22float2(v3.a), g3 = __half22float2(v3.b);
        float2 f4 = __half22float2(v4.a), g4 = __half22float2(v4.b);
        float2 f5 = __half22float2(v5.a), g5 = __half22float2(v5.b);
        float2 f6 = __half22float2(v6.a), g6 = __half22float2(v6.b);
        float2 f7 = __half22float2(v7.a), g7 = __half22float2(v7.b);
        a0 += ((f0.x + f1.x) + (f2.x + f3.x)) + ((f4.x + f5.x) + (f6.x + f7.x));
        a1 += ((f0.y + f1.y) + (f2.y + f3.y)) + ((f4.y + f5.y) + (f6.y + f7.y));
        a2 += ((g0.x + g1.x) + (g2.x + g3.x)) + ((g4.x + g5.x) + (g6.x + g7.x));
        a3 += ((g0.y + g1.y) + (g2.y + g3.y)) + ((g4.y + g5.y) + (g6.y + g7.y));
    }
    for (; k + 1 < end; k += 2) {
        int s0 = __builtin_nontemporal_load(csr_src + k);
        int s1 = __builtin_nontemporal_load(csr_src + k + 1);
        h4 v0 = xs4[(size_t)s0 * 16 + c8];
        h4 v1 = xs4[(size_t)s1 * 16 + c8];
        float2 f0 = __half22float2(v0.a), g0 = __half22float2(v0.b);
        float2 f1 = __half22float2(v1.a), g1 = __half22float2(v1.b);
        a0 += f0.x + f1.x; a1 += f0.y + f1.y;
        a2 += g0.x + g1.x; a3 += g0.y + g1.y;
    }
    if (k < end) {
        int s0 = __builtin_nontemporal_load(csr_src + k);
        h4 v0 = xs4[(size_t)s0 * 16 + c8];
        float2 f0 = __half22float2(v0.a), g0 = __half22float2(v0.b);
        a0 += f0.x; a1 += f0.y; a2 += g0.x; a3 += g0.y;
    }
    float dd = dis[node];
    f4v o = { a0 * dd, a1 * dd, a2 * dd, a3 * dd };
    __builtin_nontemporal_store(o, (f4v*)(out + (size_t)node * DFEAT + c8 * 4));
}

// ---------------- fallback (atomic scatter) if ws too small ----------------
__global__ void fb_deg_kernel(const int* __restrict__ dst,
                              float* __restrict__ deg, int E, int N) {
    int e = blockIdx.x * blockDim.x + threadIdx.x;
    if (e < E) {
        unsigned d = (unsigned)dst[e];
        if (d < (unsigned)N) unsafeAtomicAdd(&deg[d], 1.0f);
    }
}
__global__ void fb_dis_kernel(float* __restrict__ deg, int N) {
    int i = blockIdx.x * blockDim.x + threadIdx.x;
    if (i < N) {
        float d = deg[i];
        deg[i] = (d > 0.0f) ? rsqrtf(d) : 0.0f;
    }
}
__global__ void fb_scatter_kernel(const float* __restrict__ x,
                                  const int* __restrict__ src,
                                  const int* __restrict__ dst,
                                  const float* __restrict__ dis,
                                  float* __restrict__ out, int E, int N) {
    long long t = (long long)blockIdx.x * blockDim.x + threadIdx.x;
    int e = (int)(t >> 4);
    int c = (int)(t & 15);
    if (e >= E) return;
    unsigned s = (unsigned)src[e];
    unsigned d = (unsigned)dst[e];
    if (s >= (unsigned)N || d >= (unsigned)N) return;
    float norm = dis[s] * dis[d];
    const float4 v = *reinterpret_cast<const float4*>(x + (size_t)s * DFEAT + c * 4);
    float* o = out + (size_t)d * DFEAT + c * 4;
    unsafeAtomicAdd(o + 0, v.x * norm);
    unsafeAtomicAdd(o + 1, v.y * norm);
    unsafeAtomicAdd(o + 2, v.z * norm);
    unsafeAtomicAdd(o + 3, v.w * norm);
}

extern "C" void kernel_launch(void* const* d_in, const int* in_sizes, int n_in,
                              void* d_out, int out_size, void* d_ws, size_t ws_size,
                              hipStream_t stream) {
    const float* x  = (const float*)d_in[0];
    const int*   ei = (const int*)d_in[1];   // harness delivers integer inputs as int32

    const int N = in_sizes[0] / DFEAT;        // 100000
    const int E = in_sizes[1] / 2;            // 1600000
    const int* src = ei;                      // row 0
    const int* dst = ei + E;                  // row 1

    float* out = (float*)d_out;

    const int NB = (N + BIN_W - 1) / BIN_W;   // bins (256 for N=100000)
    const int NT = (E + TILE - 1) / TILE;     // tiles (196 for E=1.6M)

    // src bucket shift: <= NBUCK buckets over [0,N)
    int bshift = 13;
    while ((((N - 1) >> bshift) + 1) > NBUCK) bshift++;

    const size_t rec_bytes = (size_t)NT * TILE * 4;
    const size_t xs_bytes  = (size_t)N * DFEAT * 2;
    auto align16 = [](size_t v) { return (v + 15) & ~(size_t)15; };

    // Path A layout (xs separate, fused staging):
    size_t szA = align16(rec_bytes) + align16(xs_bytes);
    // Path B layout (xs overlays records):
    size_t szB = align16(rec_bytes > xs_bytes ? rec_bytes : xs_bytes);
    size_t tail = align16((size_t)NT * DIRW * 4) + align16(256 * 4) +
                  align16((size_t)N * 4) + align16((size_t)(N + 1) * 4) +
                  align16((size_t)E * 4);
    szA += tail; szB += tail;

    const bool structural = (NB <= 256) && (NT <= MAX_NT) && (NT <= K3_THREADS) &&
                            (N <= (1 << 23)) && (BIN_W <= 512);
    const bool pathA = structural && (szA <= ws_size);
    const bool pathB = structural && !pathA && (szB <= ws_size) &&
                       (rec_bytes <= szB - tail) && (xs_bytes <= szB - tail);

    if (pathA || pathB) {
        char* base = (char*)d_ws;
        size_t off = 0;
        auto alloc = [&](size_t bytes) { void* p = base + off; off += align16(bytes); return p; };

        u32* records; h4* xsA = nullptr; __half2* xsB = nullptr;
        if (pathA) {
            records = (u32*)alloc(rec_bytes);
            xsA     = (h4*)alloc(xs_bytes);
        } else {
            records = (u32*)alloc(rec_bytes > xs_bytes ? rec_bytes : xs_bytes);
            xsB     = (__half2*)records;       // overlay; records dead after K3
        }
        int*   dir      = (int*)alloc((size_t)NT * DIRW * 4);
        int*   bin_cnt  = (int*)alloc(256 * 4);
        float* dis      = (float*)alloc((size_t)N * 4);
        int*   row_ptr  = (int*)alloc((size_t)(N + 1) * 4);
        int*   csr_src  = (int*)alloc((size_t)E * 4);

        zero_kernel<<<1, 256, 0, stream>>>(bin_cnt, 256);
        bin_kernel<<<NT, K1_THREADS, 0, stream>>>(src, dst, records, dir, bin_cnt, E, N);
        csr_build_kernel<<<NB, K3_THREADS, 0, stream>>>(records, dir, bin_cnt, dis,
                                                        row_ptr, csr_src, x, xsA,
                                                        N, NT, NB, bshift);
        const h4* xs_final;
        if (pathA) {
            xs_final = xsA;
        } else {
            int total4 = N * DFEAT / 4;
            stage_xs_kernel<<<(total4 + 255) / 256, 256, 0, stream>>>(x, dis, xsB, total4);
            xs_final = (const h4*)xsB;
        }

        int gblocks = (N + 15) / 16;   // 16 nodes per 256-thread block
        gather_s_kernel<<<gblocks, 256, 0, stream>>>(xs_final, row_ptr, csr_src, dis, out, N);
    } else {
        // fallback: atomic scatter (needs only N floats of ws)
        float* deg = (float*)d_ws;
        hipMemsetAsync(deg, 0, (size_t)N * 4, stream);
        hipMemsetAsync(out, 0, (size_t)out_size * 4, stream);
        int eb = (E + 255) / 256;
        fb_deg_kernel<<<eb, 256, 0, stream>>>(dst, deg, E, N);
        int nb = (N + 255) / 256;
        fb_dis_kernel<<<nb, 256, 0, stream>>>(deg, N);
        long long total = (long long)E * 16;
        int sb = (int)((total + 255) / 256);
        fb_scatter_kernel<<<sb, 256, 0, stream>>>(x, src, dst, deg, out, E, N);
    }
}